// Round 12
// baseline (322.406 us; speedup 1.0000x reference)
//
#include <hip/hip_runtime.h>

// GAT link predictor forward, MI355X/gfx950.
//   k_gemm   : h = x @ W via bf16 MFMA -> h8 [N][256] fp8-e4m3; W fragments
//              in VGPRs (no LDS); fused a_src/a_dst epilogue (head = cg).
//   CSR build (ZERO device atomics -- r11 showed per-edge device atomics +
//   random 4B scatter = 96MB line-granularity writes @780GB/s = 131us):
//     k_hist    per-block LDS histogram over 1563 buckets (dst>>6)
//     k_colscan per-bucket scan over blocks (in-place) + totals
//     k_bscan   exclusive scan of totals -> base[]
//     k_scat    LDS-cursor scatter of (dst,src) pairs into block-reserved
//               contiguous sub-ranges of bucket regions
//     k_bsort   per-bucket (64 nodes) LDS count+prefix -> rowptr + dense csr
//   k_main   : 1 wave/node (3 grid-thirds for profiler visibility);
//              self-loop inline; ev recomputed from L2-resident a_src/a_dst
//              (softmax shift-invariant, no max pass); per edge: 4B csr +
//              4B a_src + 256B fp8 h-row gather, HW fp8 decode.

#define NN 100000
#define IN_DIM 128
#define HC 256            // H*C = 4*64
#define NEG_SLOPE 0.2f
#define NB 1563           // ceil(NN/64) buckets of 64 nodes
#define HB 128            // edge-chunk blocks for hist/scat

typedef __attribute__((ext_vector_type(8))) __bf16 bf16x8;
typedef __attribute__((ext_vector_type(4))) float f32x4;
typedef __attribute__((ext_vector_type(2))) float f32x2;

// ---------------- GEMM: h = x @ W (bf16 MFMA, no LDS) --------------------
__global__ __launch_bounds__(256, 4) void k_gemm(const float* __restrict__ x,
    const float* __restrict__ W, const float* __restrict__ att_src,
    const float* __restrict__ att_dst, unsigned char* __restrict__ h8,
    float* __restrict__ a_src, float* __restrict__ a_dst, int n_tiles) {
  const int tid = threadIdx.x;
  const int cg = blockIdx.x & 3;
  const int rblk = blockIdx.x >> 2;          // 0..255
  const int wave = tid >> 6, lane = tid & 63;
  const int g = lane >> 4, i16 = lane & 15;

  bf16x8 wf[4][4];                           // [nt][kk], 64 VGPR
  float as_l[4], ad_l[4];
  #pragma unroll
  for (int nt = 0; nt < 4; ++nt) {
    const int col = cg * 64 + nt * 16 + i16;
    as_l[nt] = att_src[col];
    ad_l[nt] = att_dst[col];
    #pragma unroll
    for (int kk = 0; kk < 4; ++kk) {
      const float* wp = W + (size_t)(kk * 32 + g * 8) * HC + col;
      bf16x8 f;
      #pragma unroll
      for (int j = 0; j < 8; ++j) f[j] = (__bf16)wp[(size_t)j * HC];
      wf[nt][kk] = f;
    }
  }

  for (int t = rblk; t < n_tiles; t += 256) {
    const int rbase = t * 64 + wave * 16;
    int arow = rbase + i16; if (arow >= NN) arow = NN - 1;  // clamp; stores guarded
    const float* xp = x + (size_t)arow * IN_DIM;
    f32x4 acc[4];
    #pragma unroll
    for (int nt = 0; nt < 4; ++nt) acc[nt] = (f32x4){0.f, 0.f, 0.f, 0.f};
    #pragma unroll
    for (int kk = 0; kk < 4; ++kk) {
      const int k0 = kk * 32 + g * 8;
      f32x4 xa = *(const f32x4*)(xp + k0);
      f32x4 xb = *(const f32x4*)(xp + k0 + 4);
      bf16x8 af;
      af[0] = (__bf16)xa[0]; af[1] = (__bf16)xa[1];
      af[2] = (__bf16)xa[2]; af[3] = (__bf16)xa[3];
      af[4] = (__bf16)xb[0]; af[5] = (__bf16)xb[1];
      af[6] = (__bf16)xb[2]; af[7] = (__bf16)xb[3];
      #pragma unroll
      for (int nt = 0; nt < 4; ++nt)
        acc[nt] = __builtin_amdgcn_mfma_f32_16x16x32_bf16(af, wf[nt][kk], acc[nt], 0, 0, 0);
    }
    float ps[4] = {0.f, 0.f, 0.f, 0.f}, pd[4] = {0.f, 0.f, 0.f, 0.f};
    #pragma unroll
    for (int nt = 0; nt < 4; ++nt) {
      #pragma unroll
      for (int r = 0; r < 4; ++r) {
        ps[r] += acc[nt][r] * as_l[nt];
        pd[r] += acc[nt][r] * ad_l[nt];
      }
    }
    #pragma unroll
    for (int r = 0; r < 4; ++r) {
      #pragma unroll
      for (int d = 1; d <= 8; d <<= 1) {     // reduce over i16
        ps[r] += __shfl_xor(ps[r], d);
        pd[r] += __shfl_xor(pd[r], d);
      }
      const int row = rbase + g * 4 + r;
      if (row < NN) {
        if (i16 == 0) {
          a_src[(size_t)row * 4 + cg] = ps[r];
          a_dst[(size_t)row * 4 + cg] = pd[r];
        }
        unsigned char* hp = h8 + (size_t)row * HC + cg * 64 + i16;
        #pragma unroll
        for (int nt = 0; nt < 4; ++nt) {
          unsigned int pv = __builtin_amdgcn_cvt_pk_fp8_f32(acc[nt][r], acc[nt][r], 0, false);
          hp[nt * 16] = (unsigned char)pv;
        }
      }
    }
  }
}

// ---------------- CSR build: bucket sort, zero device atomics -------------
__global__ __launch_bounds__(256) void k_hist(const int* __restrict__ ei,
    int* __restrict__ bh, int e0, int ch) {
  __shared__ int h[NB];
  const int b = blockIdx.x, tid = threadIdx.x;
  for (int k = tid; k < NB; k += 256) h[k] = 0;
  __syncthreads();
  const int lo = b * ch, hi = min(lo + ch, e0);
  for (int e = lo + tid; e < hi; e += 256)
    atomicAdd(&h[((unsigned)ei[e0 + e]) >> 6], 1);    // LDS atomic
  __syncthreads();
  for (int k = tid; k < NB; k += 256) bh[(size_t)b * NB + k] = h[k];
}

__global__ __launch_bounds__(256) void k_colscan(int* __restrict__ bh,
                                                 int* __restrict__ total) {
  int k = blockIdx.x * 256 + threadIdx.x;
  if (k >= NB) return;
  int run = 0;
  for (int b = 0; b < HB; ++b) {
    size_t i = (size_t)b * NB + k;
    int t = bh[i]; bh[i] = run; run += t;
  }
  total[k] = run;
}

__global__ __launch_bounds__(256) void k_bscan(const int* __restrict__ total,
                                               int* __restrict__ base, int e0) {
  __shared__ int ls[256];
  const int t = threadIdx.x;
  int vals[7]; int lsum = 0;
  #pragma unroll
  for (int i = 0; i < 7; ++i) {
    int k = t * 7 + i;
    vals[i] = (k < NB) ? total[k] : 0;
    lsum += vals[i];
  }
  ls[t] = lsum; __syncthreads();
  for (int off = 1; off < 256; off <<= 1) {
    int v = (t >= off) ? ls[t - off] : 0;
    __syncthreads(); ls[t] += v; __syncthreads();
  }
  int excl = (t == 0) ? 0 : ls[t - 1];
  #pragma unroll
  for (int i = 0; i < 7; ++i) {
    int k = t * 7 + i;
    if (k < NB) base[k] = excl;
    excl += vals[i];
  }
  if (t == 255) base[NB] = e0;
}

__global__ __launch_bounds__(256) void k_scat(const int* __restrict__ ei,
    const int* __restrict__ bh, const int* __restrict__ base,
    uint2* __restrict__ rec, int e0, int ch) {
  __shared__ int cur[NB];
  const int b = blockIdx.x, tid = threadIdx.x;
  for (int k = tid; k < NB; k += 256)
    cur[k] = base[k] + bh[(size_t)b * NB + k];
  __syncthreads();
  const int lo = b * ch, hi = min(lo + ch, e0);
  for (int e = lo + tid; e < hi; e += 256) {
    int s = ei[e], d = ei[e0 + e];
    int p = atomicAdd(&cur[((unsigned)d) >> 6], 1);   // LDS atomic
    rec[p] = (uint2){(unsigned)d, (unsigned)s};
  }
}

__global__ __launch_bounds__(256) void k_bsort(const uint2* __restrict__ rec,
    const int* __restrict__ base, int* __restrict__ csr,
    int* __restrict__ rowptr, int e0) {
  __shared__ int cnt64[64], pre[64];
  const int k = blockIdx.x, tid = threadIdx.x;
  const int lo = base[k], hi = base[k + 1];
  if (tid < 64) cnt64[tid] = 0;
  __syncthreads();
  for (int i = lo + tid; i < hi; i += 256)
    atomicAdd(&cnt64[rec[i].x & 63], 1);              // LDS atomic
  __syncthreads();
  if (tid == 0) {
    int run = 0;
    for (int j = 0; j < 64; ++j) { pre[j] = run; run += cnt64[j]; }
  }
  __syncthreads();
  if (tid < 64) {
    int n = k * 64 + tid;
    if (n < NN) rowptr[n] = lo + pre[tid];
    cnt64[tid] = lo + pre[tid];                       // becomes cursor
  }
  if (k == NB - 1 && tid == 0) rowptr[NN] = e0;
  __syncthreads();
  for (int i = lo + tid; i < hi; i += 256) {          // rec re-read: L2-hot
    uint2 r = rec[i];
    int p = atomicAdd(&cnt64[r.x & 63], 1);           // LDS atomic
    csr[p] = (int)r.y;
  }
}

// ------------------- main: per-dst aggregate ------------------------------
__global__ __launch_bounds__(256) void k_main(const unsigned char* __restrict__ h8,
    const float* __restrict__ a_src, const float* __restrict__ a_dst,
    const int* __restrict__ rowptr, const int* __restrict__ csr,
    const float* __restrict__ bias, const float* __restrict__ fc_w,
    const float* __restrict__ fc_b, float* __restrict__ out, int n0) {
  const int tid = threadIdx.x, lane = tid & 63;
  const int n = n0 + blockIdx.x * 4 + (tid >> 6);   // 1 node per wave
  if (n >= NN) return;
  const int eh = lane >> 5;
  const int c8 = lane & 31;
  const int head = c8 >> 3;
  const float wz = ((c8 & 7) == 0) ? 1.f : 0.f;     // one z-lane per (edge,head)
  const unsigned char* __restrict__ hb = h8 + c8 * 8;
  const float adh = a_dst[n * 4 + head];
  const int beg = rowptr[n];
  const int end = rowptr[n + 1];
  const int ne = end - beg;

  // self-loop init (eh==0 lanes carry it; merged by shfl_xor(32) below)
  float a0, a1, a2, a3, a4, a5, a6, a7, zl;
  {
    float lg = a_src[n * 4 + head] + adh;
    lg = fmaxf(lg, NEG_SLOPE * lg);
    const float ev = (eh == 0) ? __expf(lg) : 0.f;
    zl = wz * ev;
    const uint2 hv = *(const uint2*)(hb + ((size_t)n << 8));
    const f32x2 f01 = __builtin_amdgcn_cvt_pk_f32_fp8(hv.x, false);
    const f32x2 f23 = __builtin_amdgcn_cvt_pk_f32_fp8(hv.x, true);
    const f32x2 f45 = __builtin_amdgcn_cvt_pk_f32_fp8(hv.y, false);
    const f32x2 f67 = __builtin_amdgcn_cvt_pk_f32_fp8(hv.y, true);
    a0 = ev * f01[0]; a1 = ev * f01[1];
    a2 = ev * f23[0]; a3 = ev * f23[1];
    a4 = ev * f45[0]; a5 = ev * f45[1];
    a6 = ev * f67[0]; a7 = ev * f67[1];
  }

  int b0 = beg;
  const int bend = beg + (ne & ~7);
  for (; b0 < bend; b0 += 8) {                      // mask-free chunks
    #pragma unroll
    for (int u = 0; u < 4; ++u) {
      const int sv = csr[b0 + u * 2 + eh];
      float lg = a_src[sv * 4 + head] + adh;
      lg = fmaxf(lg, NEG_SLOPE * lg);               // leaky_relu
      const float ev = __expf(lg);
      zl += wz * ev;
      const uint2 hv = *(const uint2*)(hb + ((size_t)sv << 8));
      const f32x2 f01 = __builtin_amdgcn_cvt_pk_f32_fp8(hv.x, false);
      const f32x2 f23 = __builtin_amdgcn_cvt_pk_f32_fp8(hv.x, true);
      const f32x2 f45 = __builtin_amdgcn_cvt_pk_f32_fp8(hv.y, false);
      const f32x2 f67 = __builtin_amdgcn_cvt_pk_f32_fp8(hv.y, true);
      a0 += ev * f01[0]; a1 += ev * f01[1];
      a2 += ev * f23[0]; a3 += ev * f23[1];
      a4 += ev * f45[0]; a5 += ev * f45[1];
      a6 += ev * f67[0]; a7 += ev * f67[1];
    }
  }
  for (; b0 < end; b0 += 2) {                       // masked tail (<8 edges)
    const int idx = b0 + eh;
    const bool v = idx < end;
    const int sv = csr[v ? idx : beg];
    float lg = a_src[sv * 4 + head] + adh;
    lg = fmaxf(lg, NEG_SLOPE * lg);
    float ev = v ? __expf(lg) : 0.f;
    zl += wz * ev;
    const uint2 hv = *(const uint2*)(hb + ((size_t)sv << 8));
    const f32x2 f01 = __builtin_amdgcn_cvt_pk_f32_fp8(hv.x, false);
    const f32x2 f23 = __builtin_amdgcn_cvt_pk_f32_fp8(hv.x, true);
    const f32x2 f45 = __builtin_amdgcn_cvt_pk_f32_fp8(hv.y, false);
    const f32x2 f67 = __builtin_amdgcn_cvt_pk_f32_fp8(hv.y, true);
    a0 += ev * f01[0]; a1 += ev * f01[1];
    a2 += ev * f23[0]; a3 += ev * f23[1];
    a4 += ev * f45[0]; a5 += ev * f45[1];
    a6 += ev * f67[0]; a7 += ev * f67[1];
  }
  // combine the two edge slots (lane ^ 32: same channels/head)
  a0 += __shfl_xor(a0, 32); a1 += __shfl_xor(a1, 32);
  a2 += __shfl_xor(a2, 32); a3 += __shfl_xor(a3, 32);
  a4 += __shfl_xor(a4, 32); a5 += __shfl_xor(a5, 32);
  a6 += __shfl_xor(a6, 32); a7 += __shfl_xor(a7, 32);
  zl += __shfl_xor(zl, 32);
  // z per head: sum + broadcast within each 8-lane octet group
  zl += __shfl_xor(zl, 1); zl += __shfl_xor(zl, 2); zl += __shfl_xor(zl, 4);
  const float rz = 0.25f / (zl + 1e-16f);           // fold head-mean /4
  a0 *= rz; a1 *= rz; a2 *= rz; a3 *= rz;
  a4 *= rz; a5 *= rz; a6 *= rz; a7 *= rz;
  // head mean: reduce over lane bits 3,4 (head select)
  a0 += __shfl_xor(a0, 8); a0 += __shfl_xor(a0, 16);
  a1 += __shfl_xor(a1, 8); a1 += __shfl_xor(a1, 16);
  a2 += __shfl_xor(a2, 8); a2 += __shfl_xor(a2, 16);
  a3 += __shfl_xor(a3, 8); a3 += __shfl_xor(a3, 16);
  a4 += __shfl_xor(a4, 8); a4 += __shfl_xor(a4, 16);
  a5 += __shfl_xor(a5, 8); a5 += __shfl_xor(a5, 16);
  a6 += __shfl_xor(a6, 8); a6 += __shfl_xor(a6, 16);
  a7 += __shfl_xor(a7, 8); a7 += __shfl_xor(a7, 16);

  const int ch0 = (c8 & 7) * 8;                     // this lane's 8 channels
  const f32x4 bv0 = *(const f32x4*)(bias + ch0);
  const f32x4 bv1 = *(const f32x4*)(bias + ch0 + 4);
  const f32x4 wv0 = *(const f32x4*)(fc_w + ch0);
  const f32x4 wv1 = *(const f32x4*)(fc_w + ch0 + 4);
  float p = fmaxf(a0 + bv0[0], 0.f) * wv0[0] + fmaxf(a1 + bv0[1], 0.f) * wv0[1]
          + fmaxf(a2 + bv0[2], 0.f) * wv0[2] + fmaxf(a3 + bv0[3], 0.f) * wv0[3]
          + fmaxf(a4 + bv1[0], 0.f) * wv1[0] + fmaxf(a5 + bv1[1], 0.f) * wv1[1]
          + fmaxf(a6 + bv1[2], 0.f) * wv1[2] + fmaxf(a7 + bv1[3], 0.f) * wv1[3];
  p += __shfl_xor(p, 1); p += __shfl_xor(p, 2); p += __shfl_xor(p, 4);
  if (lane == 0) out[n] = 1.f / (1.f + __expf(-(p + fc_b[0])));
}

// -------------------------------------------------------------------------
extern "C" void kernel_launch(void* const* d_in, const int* in_sizes, int n_in,
                              void* d_out, int out_size, void* d_ws, size_t ws_size,
                              hipStream_t stream) {
  const float* x       = (const float*)d_in[0];
  const int*   ei      = (const int*)d_in[1];   // [2][E0] int32
  const float* W       = (const float*)d_in[2];
  const float* att_src = (const float*)d_in[3];
  const float* att_dst = (const float*)d_in[4];
  const float* bias    = (const float*)d_in[5];
  const float* fc_w    = (const float*)d_in[6];
  const float* fc_b    = (const float*)d_in[7];
  float* out = (float*)d_out;
  const int e0 = in_sizes[1] / 2;

  char* ws = (char*)d_ws;
  size_t off = 0;
  auto carve = [&](size_t bytes) {
    void* p = ws + off;
    off = (off + bytes + 255) & ~(size_t)255;
    return p;
  };
  unsigned char* h8 = (unsigned char*)carve((size_t)NN * HC);       // 25.6 MB
  float* a_src = (float*)carve((size_t)NN * 4 * 4);
  float* a_dst = (float*)carve((size_t)NN * 4 * 4);
  int* bh      = (int*)carve((size_t)HB * NB * 4);                  // 800 KB
  int* total   = (int*)carve((size_t)NB * 4);
  int* base    = (int*)carve((size_t)(NB + 1) * 4);
  int* rowptr  = (int*)carve((size_t)(NN + 1) * 4);
  uint2* rec   = (uint2*)carve((size_t)e0 * 8);                     // 12.8 MB
  int* csrbuf  = (int*)carve((size_t)e0 * 4);                       // 6.4 MB

  const int n_tiles = (NN + 63) / 64;                 // 1563
  const int ch = (e0 + HB - 1) / HB;                  // edges per chunk block
  k_gemm<<<dim3(1024), dim3(256), 0, stream>>>(x, W, att_src, att_dst,
                                               h8, a_src, a_dst, n_tiles);
  k_hist<<<dim3(HB), dim3(256), 0, stream>>>(ei, bh, e0, ch);
  k_colscan<<<dim3((NB + 255) / 256), dim3(256), 0, stream>>>(bh, total);
  k_bscan<<<dim3(1), dim3(256), 0, stream>>>(total, base, e0);
  k_scat<<<dim3(HB), dim3(256), 0, stream>>>(ei, bh, base, rec, e0, ch);
  k_bsort<<<dim3(NB), dim3(256), 0, stream>>>(rec, base, csrbuf, rowptr, e0);
  // k_main in 3 grid-thirds (keeps tier-2 kernels visible in top-5)
  const int third = 8334;                             // 8334*4 = 33336 nodes
  k_main<<<dim3(third), dim3(256), 0, stream>>>(h8, a_src, a_dst, rowptr, csrbuf,
                                                bias, fc_w, fc_b, out, 0);
  k_main<<<dim3(third), dim3(256), 0, stream>>>(h8, a_src, a_dst, rowptr, csrbuf,
                                                bias, fc_w, fc_b, out, 33336);
  k_main<<<dim3(8333), dim3(256), 0, stream>>>(h8, a_src, a_dst, rowptr, csrbuf,
                                               bias, fc_w, fc_b, out, 66672);
}

// Round 13
// 306.671 us; speedup vs baseline: 1.0513x; 1.0513x over previous
//
#include <hip/hip_runtime.h>

// GAT link predictor forward, MI355X/gfx950.
//   k_gemm   : h = x @ W via bf16 MFMA -> h8 [N][256] fp8-e4m3; W fragments
//              in VGPRs (no LDS); fused a_src/a_dst epilogue (head = cg).
//              Grid 2048 (8 blk/CU at 64 VGPR); XCD-aware bid remap so the
//              4 col-groups of one row-block share an XCD L2 (x fetch 1x).
//   CSR build (zero device atomics; r11: device-atomic scatter = 131us):
//     k_hist    512 blocks, LDS histogram over 1563 buckets (dst>>6)
//     k_colscan one WAVE per bucket: shfl_up scan over 512 block counts
//     k_bscan   exclusive scan of totals -> base[]
//     k_scat    512 blocks, LDS-cursor scatter of (dst,src) into
//               block-reserved contiguous sub-ranges
//     k_bsort   per-bucket (64 nodes) LDS count+prefix -> rowptr + dense csr
//   k_main   : 1 wave/node (3 grid-thirds for profiler visibility);
//              self-loop inline; ev recomputed from L2-resident a_src/a_dst
//              (softmax shift-invariant, no max pass); per edge: 4B csr +
//              4B a_src + 256B fp8 h-row gather, HW fp8 decode.

#define NN 100000
#define IN_DIM 128
#define HC 256            // H*C = 4*64
#define NEG_SLOPE 0.2f
#define NB 1563           // ceil(NN/64) buckets of 64 nodes
#define HB 512            // edge-chunk blocks for hist/scat

typedef __attribute__((ext_vector_type(8))) __bf16 bf16x8;
typedef __attribute__((ext_vector_type(4))) float f32x4;
typedef __attribute__((ext_vector_type(2))) float f32x2;

// ---------------- GEMM: h = x @ W (bf16 MFMA, no LDS) --------------------
__global__ __launch_bounds__(256, 4) void k_gemm(const float* __restrict__ x,
    const float* __restrict__ W, const float* __restrict__ att_src,
    const float* __restrict__ att_dst, unsigned char* __restrict__ h8,
    float* __restrict__ a_src, float* __restrict__ a_dst, int n_tiles) {
  const int tid = threadIdx.x;
  const int bid = blockIdx.x;               // 0..2047
  // XCD-aware remap: blocks b, b+8, b+16, b+24 land on the same XCD
  // (bid % 8 = XCD round-robin heuristic). Give the 4 col-groups of one
  // row-block bids that differ by 8 -> they share the x rows in one L2.
  const int cg = (bid >> 3) & 3;
  const int rblk = (bid & 7) | ((bid >> 5) << 3);   // 0..511, bijective
  const int wave = tid >> 6, lane = tid & 63;
  const int g = lane >> 4, i16 = lane & 15;

  bf16x8 wf[4][4];                           // [nt][kk], 64 VGPR
  float as_l[4], ad_l[4];
  #pragma unroll
  for (int nt = 0; nt < 4; ++nt) {
    const int col = cg * 64 + nt * 16 + i16;
    as_l[nt] = att_src[col];
    ad_l[nt] = att_dst[col];
    #pragma unroll
    for (int kk = 0; kk < 4; ++kk) {
      const float* wp = W + (size_t)(kk * 32 + g * 8) * HC + col;
      bf16x8 f;
      #pragma unroll
      for (int j = 0; j < 8; ++j) f[j] = (__bf16)wp[(size_t)j * HC];
      wf[nt][kk] = f;
    }
  }

  for (int t = rblk; t < n_tiles; t += 512) {
    const int rbase = t * 64 + wave * 16;
    int arow = rbase + i16; if (arow >= NN) arow = NN - 1;  // clamp; stores guarded
    const float* xp = x + (size_t)arow * IN_DIM;
    f32x4 acc[4];
    #pragma unroll
    for (int nt = 0; nt < 4; ++nt) acc[nt] = (f32x4){0.f, 0.f, 0.f, 0.f};
    #pragma unroll
    for (int kk = 0; kk < 4; ++kk) {
      const int k0 = kk * 32 + g * 8;
      f32x4 xa = *(const f32x4*)(xp + k0);
      f32x4 xb = *(const f32x4*)(xp + k0 + 4);
      bf16x8 af;
      af[0] = (__bf16)xa[0]; af[1] = (__bf16)xa[1];
      af[2] = (__bf16)xa[2]; af[3] = (__bf16)xa[3];
      af[4] = (__bf16)xb[0]; af[5] = (__bf16)xb[1];
      af[6] = (__bf16)xb[2]; af[7] = (__bf16)xb[3];
      #pragma unroll
      for (int nt = 0; nt < 4; ++nt)
        acc[nt] = __builtin_amdgcn_mfma_f32_16x16x32_bf16(af, wf[nt][kk], acc[nt], 0, 0, 0);
    }
    float ps[4] = {0.f, 0.f, 0.f, 0.f}, pd[4] = {0.f, 0.f, 0.f, 0.f};
    #pragma unroll
    for (int nt = 0; nt < 4; ++nt) {
      #pragma unroll
      for (int r = 0; r < 4; ++r) {
        ps[r] += acc[nt][r] * as_l[nt];
        pd[r] += acc[nt][r] * ad_l[nt];
      }
    }
    #pragma unroll
    for (int r = 0; r < 4; ++r) {
      #pragma unroll
      for (int d = 1; d <= 8; d <<= 1) {     // reduce over i16
        ps[r] += __shfl_xor(ps[r], d);
        pd[r] += __shfl_xor(pd[r], d);
      }
      const int row = rbase + g * 4 + r;
      if (row < NN) {
        if (i16 == 0) {
          a_src[(size_t)row * 4 + cg] = ps[r];
          a_dst[(size_t)row * 4 + cg] = pd[r];
        }
        unsigned char* hp = h8 + (size_t)row * HC + cg * 64 + i16;
        #pragma unroll
        for (int nt = 0; nt < 4; ++nt) {
          unsigned int pv = __builtin_amdgcn_cvt_pk_fp8_f32(acc[nt][r], acc[nt][r], 0, false);
          hp[nt * 16] = (unsigned char)pv;
        }
      }
    }
  }
}

// ---------------- CSR build: bucket sort, zero device atomics -------------
__global__ __launch_bounds__(256) void k_hist(const int* __restrict__ ei,
    int* __restrict__ bh, int e0, int ch) {
  __shared__ int h[NB];
  const int b = blockIdx.x, tid = threadIdx.x;
  for (int k = tid; k < NB; k += 256) h[k] = 0;
  __syncthreads();
  const int lo = b * ch, hi = min(lo + ch, e0);
  for (int e = lo + tid; e < hi; e += 256)
    atomicAdd(&h[((unsigned)ei[e0 + e]) >> 6], 1);    // LDS atomic
  __syncthreads();
  for (int k = tid; k < NB; k += 256) bh[(size_t)b * NB + k] = h[k];
}

// one wave per bucket: shfl_up scan over HB=512 block counts (8 per lane)
__global__ __launch_bounds__(256) void k_colscan(int* __restrict__ bh,
                                                 int* __restrict__ total) {
  const int wv = blockIdx.x * 4 + (threadIdx.x >> 6);  // bucket id
  if (wv >= NB) return;
  const int lane = threadIdx.x & 63;
  int v[8]; int s = 0;
  #pragma unroll
  for (int i = 0; i < 8; ++i) {
    v[i] = bh[(size_t)(lane * 8 + i) * NB + wv];
    s += v[i];
  }
  int run = s;                                         // inclusive lane scan
  #pragma unroll
  for (int d = 1; d < 64; d <<= 1) {
    int t = __shfl_up(run, d);
    if (lane >= d) run += t;
  }
  int acc = run - s;                                   // exclusive prefix
  #pragma unroll
  for (int i = 0; i < 8; ++i) {
    int t = v[i];
    bh[(size_t)(lane * 8 + i) * NB + wv] = acc;
    acc += t;
  }
  if (lane == 63) total[wv] = acc;
}

__global__ __launch_bounds__(256) void k_bscan(const int* __restrict__ total,
                                               int* __restrict__ base, int e0) {
  __shared__ int ls[256];
  const int t = threadIdx.x;
  int vals[7]; int lsum = 0;
  #pragma unroll
  for (int i = 0; i < 7; ++i) {
    int k = t * 7 + i;
    vals[i] = (k < NB) ? total[k] : 0;
    lsum += vals[i];
  }
  ls[t] = lsum; __syncthreads();
  for (int off = 1; off < 256; off <<= 1) {
    int v = (t >= off) ? ls[t - off] : 0;
    __syncthreads(); ls[t] += v; __syncthreads();
  }
  int excl = (t == 0) ? 0 : ls[t - 1];
  #pragma unroll
  for (int i = 0; i < 7; ++i) {
    int k = t * 7 + i;
    if (k < NB) base[k] = excl;
    excl += vals[i];
  }
  if (t == 255) base[NB] = e0;
}

__global__ __launch_bounds__(256) void k_scat(const int* __restrict__ ei,
    const int* __restrict__ bh, const int* __restrict__ base,
    uint2* __restrict__ rec, int e0, int ch) {
  __shared__ int cur[NB];
  const int b = blockIdx.x, tid = threadIdx.x;
  for (int k = tid; k < NB; k += 256)
    cur[k] = base[k] + bh[(size_t)b * NB + k];
  __syncthreads();
  const int lo = b * ch, hi = min(lo + ch, e0);
  for (int e = lo + tid; e < hi; e += 256) {
    int s = ei[e], d = ei[e0 + e];
    int p = atomicAdd(&cur[((unsigned)d) >> 6], 1);   // LDS atomic
    rec[p] = (uint2){(unsigned)d, (unsigned)s};
  }
}

__global__ __launch_bounds__(256) void k_bsort(const uint2* __restrict__ rec,
    const int* __restrict__ base, int* __restrict__ csr,
    int* __restrict__ rowptr, int e0) {
  __shared__ int cnt64[64], pre[64];
  const int k = blockIdx.x, tid = threadIdx.x;
  const int lo = base[k], hi = base[k + 1];
  if (tid < 64) cnt64[tid] = 0;
  __syncthreads();
  for (int i = lo + tid; i < hi; i += 256)
    atomicAdd(&cnt64[rec[i].x & 63], 1);              // LDS atomic
  __syncthreads();
  if (tid == 0) {
    int run = 0;
    for (int j = 0; j < 64; ++j) { pre[j] = run; run += cnt64[j]; }
  }
  __syncthreads();
  if (tid < 64) {
    int n = k * 64 + tid;
    if (n < NN) rowptr[n] = lo + pre[tid];
    cnt64[tid] = lo + pre[tid];                       // becomes cursor
  }
  if (k == NB - 1 && tid == 0) rowptr[NN] = e0;
  __syncthreads();
  for (int i = lo + tid; i < hi; i += 256) {          // rec re-read: L2-hot
    uint2 r = rec[i];
    int p = atomicAdd(&cnt64[r.x & 63], 1);           // LDS atomic
    csr[p] = (int)r.y;
  }
}

// ------------------- main: per-dst aggregate ------------------------------
__global__ __launch_bounds__(256) void k_main(const unsigned char* __restrict__ h8,
    const float* __restrict__ a_src, const float* __restrict__ a_dst,
    const int* __restrict__ rowptr, const int* __restrict__ csr,
    const float* __restrict__ bias, const float* __restrict__ fc_w,
    const float* __restrict__ fc_b, float* __restrict__ out, int n0) {
  const int tid = threadIdx.x, lane = tid & 63;
  const int n = n0 + blockIdx.x * 4 + (tid >> 6);   // 1 node per wave
  if (n >= NN) return;
  const int eh = lane >> 5;
  const int c8 = lane & 31;
  const int head = c8 >> 3;
  const float wz = ((c8 & 7) == 0) ? 1.f : 0.f;     // one z-lane per (edge,head)
  const unsigned char* __restrict__ hb = h8 + c8 * 8;
  const float adh = a_dst[n * 4 + head];
  const int beg = rowptr[n];
  const int end = rowptr[n + 1];
  const int ne = end - beg;

  // self-loop init (eh==0 lanes carry it; merged by shfl_xor(32) below)
  float a0, a1, a2, a3, a4, a5, a6, a7, zl;
  {
    float lg = a_src[n * 4 + head] + adh;
    lg = fmaxf(lg, NEG_SLOPE * lg);
    const float ev = (eh == 0) ? __expf(lg) : 0.f;
    zl = wz * ev;
    const uint2 hv = *(const uint2*)(hb + ((size_t)n << 8));
    const f32x2 f01 = __builtin_amdgcn_cvt_pk_f32_fp8(hv.x, false);
    const f32x2 f23 = __builtin_amdgcn_cvt_pk_f32_fp8(hv.x, true);
    const f32x2 f45 = __builtin_amdgcn_cvt_pk_f32_fp8(hv.y, false);
    const f32x2 f67 = __builtin_amdgcn_cvt_pk_f32_fp8(hv.y, true);
    a0 = ev * f01[0]; a1 = ev * f01[1];
    a2 = ev * f23[0]; a3 = ev * f23[1];
    a4 = ev * f45[0]; a5 = ev * f45[1];
    a6 = ev * f67[0]; a7 = ev * f67[1];
  }

  int b0 = beg;
  const int bend = beg + (ne & ~7);
  for (; b0 < bend; b0 += 8) {                      // mask-free chunks
    #pragma unroll
    for (int u = 0; u < 4; ++u) {
      const int sv = csr[b0 + u * 2 + eh];
      float lg = a_src[sv * 4 + head] + adh;
      lg = fmaxf(lg, NEG_SLOPE * lg);               // leaky_relu
      const float ev = __expf(lg);
      zl += wz * ev;
      const uint2 hv = *(const uint2*)(hb + ((size_t)sv << 8));
      const f32x2 f01 = __builtin_amdgcn_cvt_pk_f32_fp8(hv.x, false);
      const f32x2 f23 = __builtin_amdgcn_cvt_pk_f32_fp8(hv.x, true);
      const f32x2 f45 = __builtin_amdgcn_cvt_pk_f32_fp8(hv.y, false);
      const f32x2 f67 = __builtin_amdgcn_cvt_pk_f32_fp8(hv.y, true);
      a0 += ev * f01[0]; a1 += ev * f01[1];
      a2 += ev * f23[0]; a3 += ev * f23[1];
      a4 += ev * f45[0]; a5 += ev * f45[1];
      a6 += ev * f67[0]; a7 += ev * f67[1];
    }
  }
  for (; b0 < end; b0 += 2) {                       // masked tail (<8 edges)
    const int idx = b0 + eh;
    const bool v = idx < end;
    const int sv = csr[v ? idx : beg];
    float lg = a_src[sv * 4 + head] + adh;
    lg = fmaxf(lg, NEG_SLOPE * lg);
    float ev = v ? __expf(lg) : 0.f;
    zl += wz * ev;
    const uint2 hv = *(const uint2*)(hb + ((size_t)sv << 8));
    const f32x2 f01 = __builtin_amdgcn_cvt_pk_f32_fp8(hv.x, false);
    const f32x2 f23 = __builtin_amdgcn_cvt_pk_f32_fp8(hv.x, true);
    const f32x2 f45 = __builtin_amdgcn_cvt_pk_f32_fp8(hv.y, false);
    const f32x2 f67 = __builtin_amdgcn_cvt_pk_f32_fp8(hv.y, true);
    a0 += ev * f01[0]; a1 += ev * f01[1];
    a2 += ev * f23[0]; a3 += ev * f23[1];
    a4 += ev * f45[0]; a5 += ev * f45[1];
    a6 += ev * f67[0]; a7 += ev * f67[1];
  }
  // combine the two edge slots (lane ^ 32: same channels/head)
  a0 += __shfl_xor(a0, 32); a1 += __shfl_xor(a1, 32);
  a2 += __shfl_xor(a2, 32); a3 += __shfl_xor(a3, 32);
  a4 += __shfl_xor(a4, 32); a5 += __shfl_xor(a5, 32);
  a6 += __shfl_xor(a6, 32); a7 += __shfl_xor(a7, 32);
  zl += __shfl_xor(zl, 32);
  // z per head: sum + broadcast within each 8-lane octet group
  zl += __shfl_xor(zl, 1); zl += __shfl_xor(zl, 2); zl += __shfl_xor(zl, 4);
  const float rz = 0.25f / (zl + 1e-16f);           // fold head-mean /4
  a0 *= rz; a1 *= rz; a2 *= rz; a3 *= rz;
  a4 *= rz; a5 *= rz; a6 *= rz; a7 *= rz;
  // head mean: reduce over lane bits 3,4 (head select)
  a0 += __shfl_xor(a0, 8); a0 += __shfl_xor(a0, 16);
  a1 += __shfl_xor(a1, 8); a1 += __shfl_xor(a1, 16);
  a2 += __shfl_xor(a2, 8); a2 += __shfl_xor(a2, 16);
  a3 += __shfl_xor(a3, 8); a3 += __shfl_xor(a3, 16);
  a4 += __shfl_xor(a4, 8); a4 += __shfl_xor(a4, 16);
  a5 += __shfl_xor(a5, 8); a5 += __shfl_xor(a5, 16);
  a6 += __shfl_xor(a6, 8); a6 += __shfl_xor(a6, 16);
  a7 += __shfl_xor(a7, 8); a7 += __shfl_xor(a7, 16);

  const int ch0 = (c8 & 7) * 8;                     // this lane's 8 channels
  const f32x4 bv0 = *(const f32x4*)(bias + ch0);
  const f32x4 bv1 = *(const f32x4*)(bias + ch0 + 4);
  const f32x4 wv0 = *(const f32x4*)(fc_w + ch0);
  const f32x4 wv1 = *(const f32x4*)(fc_w + ch0 + 4);
  float p = fmaxf(a0 + bv0[0], 0.f) * wv0[0] + fmaxf(a1 + bv0[1], 0.f) * wv0[1]
          + fmaxf(a2 + bv0[2], 0.f) * wv0[2] + fmaxf(a3 + bv0[3], 0.f) * wv0[3]
          + fmaxf(a4 + bv1[0], 0.f) * wv1[0] + fmaxf(a5 + bv1[1], 0.f) * wv1[1]
          + fmaxf(a6 + bv1[2], 0.f) * wv1[2] + fmaxf(a7 + bv1[3], 0.f) * wv1[3];
  p += __shfl_xor(p, 1); p += __shfl_xor(p, 2); p += __shfl_xor(p, 4);
  if (lane == 0) out[n] = 1.f / (1.f + __expf(-(p + fc_b[0])));
}

// -------------------------------------------------------------------------
extern "C" void kernel_launch(void* const* d_in, const int* in_sizes, int n_in,
                              void* d_out, int out_size, void* d_ws, size_t ws_size,
                              hipStream_t stream) {
  const float* x       = (const float*)d_in[0];
  const int*   ei      = (const int*)d_in[1];   // [2][E0] int32
  const float* W       = (const float*)d_in[2];
  const float* att_src = (const float*)d_in[3];
  const float* att_dst = (const float*)d_in[4];
  const float* bias    = (const float*)d_in[5];
  const float* fc_w    = (const float*)d_in[6];
  const float* fc_b    = (const float*)d_in[7];
  float* out = (float*)d_out;
  const int e0 = in_sizes[1] / 2;

  char* ws = (char*)d_ws;
  size_t off = 0;
  auto carve = [&](size_t bytes) {
    void* p = ws + off;
    off = (off + bytes + 255) & ~(size_t)255;
    return p;
  };
  unsigned char* h8 = (unsigned char*)carve((size_t)NN * HC);       // 25.6 MB
  float* a_src = (float*)carve((size_t)NN * 4 * 4);
  float* a_dst = (float*)carve((size_t)NN * 4 * 4);
  int* bh      = (int*)carve((size_t)HB * NB * 4);                  // 3.2 MB
  int* total   = (int*)carve((size_t)NB * 4);
  int* base    = (int*)carve((size_t)(NB + 1) * 4);
  int* rowptr  = (int*)carve((size_t)(NN + 1) * 4);
  uint2* rec   = (uint2*)carve((size_t)e0 * 8);                     // 12.8 MB
  int* csrbuf  = (int*)carve((size_t)e0 * 4);                       // 6.4 MB

  const int n_tiles = (NN + 63) / 64;                 // 1563
  const int ch = (e0 + HB - 1) / HB;                  // edges per chunk block
  k_gemm<<<dim3(2048), dim3(256), 0, stream>>>(x, W, att_src, att_dst,
                                               h8, a_src, a_dst, n_tiles);
  k_hist<<<dim3(HB), dim3(256), 0, stream>>>(ei, bh, e0, ch);
  k_colscan<<<dim3((NB + 3) / 4), dim3(256), 0, stream>>>(bh, total);
  k_bscan<<<dim3(1), dim3(256), 0, stream>>>(total, base, e0);
  k_scat<<<dim3(HB), dim3(256), 0, stream>>>(ei, bh, base, rec, e0, ch);
  k_bsort<<<dim3(NB), dim3(256), 0, stream>>>(rec, base, csrbuf, rowptr, e0);
  // k_main in 3 grid-thirds (keeps tier-2 kernels visible in top-5)
  const int third = 8334;                             // 8334*4 = 33336 nodes
  k_main<<<dim3(third), dim3(256), 0, stream>>>(h8, a_src, a_dst, rowptr, csrbuf,
                                                bias, fc_w, fc_b, out, 0);
  k_main<<<dim3(third), dim3(256), 0, stream>>>(h8, a_src, a_dst, rowptr, csrbuf,
                                                bias, fc_w, fc_b, out, 33336);
  k_main<<<dim3(8333), dim3(256), 0, stream>>>(h8, a_src, a_dst, rowptr, csrbuf,
                                               bias, fc_w, fc_b, out, 66672);
}